// Round 1
// baseline (225.943 us; speedup 1.0000x reference)
//
#include <hip/hip_runtime.h>

#define B_SZ   8
#define SEQ    2048
#define SDIM   1024
#define DIN    512
#define DOUT   512
#define KX     10
#define RTOT   (B_SZ*SEQ)   // 16384
#define LC     64
#define NC     (SEQ/LC)     // 32

typedef __attribute__((ext_vector_type(8))) short short8;
typedef __attribute__((ext_vector_type(4))) float f32x4;

// ---- workspace layout (bytes) ----
#define OFF_XBF  0UL            // RTOT*DIN*2   = 16777216
#define OFF_UB   16777216UL     // RTOT*SDIM*4  = 67108864
#define OFF_HS   83886080UL     // RTOT*SDIM*2  = 33554432
#define OFF_BT   117440512UL    // SDIM*DIN*2   = 1048576
#define OFF_CT   118489088UL    // DOUT*SDIM*2  = 1048576
#define OFF_MT   119537664UL    // KX*DOUT*DIN*2= 5242880
#define OFF_E    124780544UL    // B_SZ*NC*SDIM*4 = 1048576
#define OFF_SB   125829120UL    // B_SZ*NC*SDIM*4 = 1048576
// total: 126877696 bytes (~121 MiB)

__device__ __forceinline__ short f2bf(float f) {
  unsigned u = __builtin_bit_cast(unsigned, f);
  u += 0x7fffu + ((u >> 16) & 1u);   // RNE
  return (short)(u >> 16);
}

// ================= conversion / prep =================
__global__ void k_conv_x(const float* __restrict__ in, short* __restrict__ out, int n8) {
  int i = blockIdx.x * blockDim.x + threadIdx.x;
  int stride = gridDim.x * blockDim.x;
  for (; i < n8; i += stride) {
    const float4* p = reinterpret_cast<const float4*>(in) + (size_t)i * 2;
    float4 f0 = p[0], f1 = p[1];
    short8 o;
    o[0]=f2bf(f0.x); o[1]=f2bf(f0.y); o[2]=f2bf(f0.z); o[3]=f2bf(f0.w);
    o[4]=f2bf(f1.x); o[5]=f2bf(f1.y); o[6]=f2bf(f1.z); o[7]=f2bf(f1.w);
    *reinterpret_cast<short8*>(out + (size_t)i * 8) = o;
  }
}

// out[j][i] = bf16(in[i][j]); in: rows x cols (both multiples of 32)
__global__ void k_transpose_bf16(const float* __restrict__ in, short* __restrict__ out,
                                 int rows, int cols) {
  __shared__ float t[32][33];
  int bx = blockIdx.x * 32, by = blockIdx.y * 32;
  int tx = threadIdx.x & 31, ty = threadIdx.x >> 5;  // 256 threads
  #pragma unroll
  for (int j = 0; j < 32; j += 8)
    t[ty + j][tx] = in[(size_t)(by + ty + j) * cols + (bx + tx)];
  __syncthreads();
  #pragma unroll
  for (int j = 0; j < 32; j += 8)
    out[(size_t)(bx + ty + j) * rows + (by + tx)] = f2bf(t[tx][ty + j]);
}

// Mt[t][o][i] = bf16(M[o][i][t])
__global__ void k_prep_M(const float* __restrict__ M, short* __restrict__ Mt) {
  int idx = blockIdx.x * 256 + threadIdx.x;
  if (idx >= DOUT * DIN) return;
  int o = idx / DIN, i = idx - o * DIN;
  const float* src = M + ((size_t)o * DIN + i) * KX;
  #pragma unroll
  for (int t = 0; t < KX; ++t)
    Mt[((size_t)t * DOUT + o) * DIN + i] = f2bf(src[t]);
}

// ================= chunked scan =================
// pass 1: E[b,c,s] = zero-state scan result over chunk c
__global__ void k_scan_E(const float* __restrict__ uB, const float* __restrict__ A,
                         float* __restrict__ E) {
  int blk = blockIdx.x, tid = threadIdx.x;
  int b = blk / NC, c = blk - b * NC;
  const float* base = uB + ((size_t)b * SEQ + (size_t)c * LC) * SDIM;
  float a[4], h[4]; int s[4];
  #pragma unroll
  for (int j = 0; j < 4; ++j) { s[j] = tid + j * 256; a[j] = A[s[j]]; h[j] = 0.f; }
  for (int t = 0; t < LC; ++t) {
    const float* rp = base + (size_t)t * SDIM;
    #pragma unroll
    for (int j = 0; j < 4; ++j) h[j] = fmaf(a[j], h[j], rp[s[j]]);
  }
  float* ep = E + (size_t)blk * SDIM;
  #pragma unroll
  for (int j = 0; j < 4; ++j) ep[s[j]] = h[j];
}

// pass 2: chunk-boundary states. Sb[b,c,s] = state BEFORE chunk c's first step
__global__ void k_scan_S(const float* __restrict__ E, const float* __restrict__ A,
                         const float* __restrict__ h0, float* __restrict__ Sb) {
  int b = blockIdx.x, tid = threadIdx.x;
  #pragma unroll
  for (int j = 0; j < 4; ++j) {
    int s = tid + j * 256;
    float a = A[s];
    float ap = a;
    #pragma unroll
    for (int q = 0; q < 6; ++q) ap *= ap;  // a^64 (LC=64)
    float S = h0[s];
    for (int c = 0; c < NC; ++c) {
      size_t idx = ((size_t)b * NC + c) * SDIM + s;
      Sb[idx] = S;
      S = fmaf(ap, S, E[idx]);
    }
  }
}

// pass 3: hs[b,t,s] (bf16) via local rescan seeded with Sb
__global__ void k_scan_h(const float* __restrict__ uB, const float* __restrict__ A,
                         const float* __restrict__ Sb, short* __restrict__ hs) {
  int blk = blockIdx.x, tid = threadIdx.x;
  int b = blk / NC, c = blk - b * NC;
  const float* base = uB + ((size_t)b * SEQ + (size_t)c * LC) * SDIM;
  short* hbase = hs + ((size_t)b * SEQ + (size_t)c * LC) * SDIM;
  float a[4], h[4]; int s[4];
  #pragma unroll
  for (int j = 0; j < 4; ++j) {
    s[j] = tid + j * 256;
    a[j] = A[s[j]];
    h[j] = Sb[(size_t)blk * SDIM + s[j]];
  }
  for (int t = 0; t < LC; ++t) {
    const float* rp = base + (size_t)t * SDIM;
    short* hp = hbase + (size_t)t * SDIM;
    #pragma unroll
    for (int j = 0; j < 4; ++j) {
      h[j] = fmaf(a[j], h[j], rp[s[j]]);
      hp[s[j]] = f2bf(h[j]);
    }
  }
}

// ================= MFMA GEMM (128x128 tile, 4 waves, BK=64) =================
__device__ __forceinline__ void stage_load(short8 r[4], const short* __restrict__ src,
                                           int ld, long row0, long rowmin, int k0, int tid) {
  const short8 zero = {0,0,0,0,0,0,0,0};
  #pragma unroll
  for (int it = 0; it < 4; ++it) {
    int ci = it * 256 + tid;
    int row = ci >> 3;
    int cc  = (ci & 7) * 8;
    long gr = row0 + row;
    r[it] = (gr >= rowmin) ? *reinterpret_cast<const short8*>(src + (size_t)gr * ld + k0 + cc)
                           : zero;
  }
}

__device__ __forceinline__ void stage_store(short (*dst)[72], const short8 r[4], int tid) {
  #pragma unroll
  for (int it = 0; it < 4; ++it) {
    int ci = it * 256 + tid;
    int row = ci >> 3;
    int cc  = (ci & 7) * 8;
    *reinterpret_cast<short8*>(&dst[row][cc]) = r[it];
  }
}

__device__ __forceinline__ void mfma_Ktile(const short (*lA)[72], const short (*lB)[72],
                                           int lane, int wm, int wn, f32x4 acc[4][4]) {
  #pragma unroll
  for (int kk = 0; kk < 64; kk += 32) {
    short8 af[4], bfr[4];
    int lr = lane & 15;
    int lk = kk + (lane >> 4) * 8;
    #pragma unroll
    for (int mi = 0; mi < 4; ++mi)
      af[mi] = *reinterpret_cast<const short8*>(&lA[wm * 64 + mi * 16 + lr][lk]);
    #pragma unroll
    for (int ni = 0; ni < 4; ++ni)
      bfr[ni] = *reinterpret_cast<const short8*>(&lB[wn * 64 + ni * 16 + lr][lk]);
    #pragma unroll
    for (int mi = 0; mi < 4; ++mi)
      #pragma unroll
      for (int ni = 0; ni < 4; ++ni)
        acc[mi][ni] = __builtin_amdgcn_mfma_f32_16x16x32_bf16(af[mi], bfr[ni], acc[mi][ni], 0, 0, 0);
  }
}

// GEMM1: uB[R,SDIM] = Xbf[R,DIN] @ Bt[SDIM,DIN]^T   (f32 out)
__global__ __launch_bounds__(256) void k_gemm_uB(const short* __restrict__ X,
                                                 const short* __restrict__ Bt,
                                                 float* __restrict__ uB) {
  __shared__ short lA[128][72];
  __shared__ short lB[128][72];
  int tid = threadIdx.x, lane = tid & 63, w = tid >> 6, wm = w >> 1, wn = w & 1;
  long r0 = (long)blockIdx.x * 128;
  int  c0 = blockIdx.y * 128;
  const f32x4 z4 = {0.f,0.f,0.f,0.f};
  f32x4 acc[4][4];
  #pragma unroll
  for (int mi = 0; mi < 4; ++mi)
    #pragma unroll
    for (int ni = 0; ni < 4; ++ni) acc[mi][ni] = z4;

  for (int k0 = 0; k0 < DIN; k0 += 64) {
    short8 ra[4], rb[4];
    stage_load(ra, X, DIN, r0, 0, k0, tid);
    stage_load(rb, Bt, DIN, (long)c0, 0, k0, tid);
    __syncthreads();
    stage_store(lA, ra, tid);
    stage_store(lB, rb, tid);
    __syncthreads();
    mfma_Ktile(lA, lB, lane, wm, wn, acc);
  }
  #pragma unroll
  for (int mi = 0; mi < 4; ++mi)
    #pragma unroll
    for (int ni = 0; ni < 4; ++ni)
      #pragma unroll
      for (int r = 0; r < 4; ++r) {
        long row = r0 + wm * 64 + mi * 16 + (lane >> 4) * 4 + r;
        int  col = c0 + wn * 64 + ni * 16 + (lane & 15);
        uB[(size_t)row * SDIM + col] = acc[mi][ni][r];
      }
}

// GEMM2: out[R,DOUT] = hs[R,SDIM] @ Ct[DOUT,SDIM]^T + sum_tap Xshift @ Mt[tap]^T
__global__ __launch_bounds__(256) void k_gemm_out(const short* __restrict__ hs,
                                                  const short* __restrict__ X,
                                                  const short* __restrict__ Ct,
                                                  const short* __restrict__ Mt,
                                                  float* __restrict__ out) {
  __shared__ short lA[128][72];
  __shared__ short lB[128][72];
  int tid = threadIdx.x, lane = tid & 63, w = tid >> 6, wm = w >> 1, wn = w & 1;
  long r0 = (long)blockIdx.x * 128;
  int  c0 = blockIdx.y * 128;
  long bstart = (r0 / SEQ) * SEQ;   // tiles never straddle batches (2048 % 128 == 0)
  const f32x4 z4 = {0.f,0.f,0.f,0.f};
  f32x4 acc[4][4];
  #pragma unroll
  for (int mi = 0; mi < 4; ++mi)
    #pragma unroll
    for (int ni = 0; ni < 4; ++ni) acc[mi][ni] = z4;

  // segment 0: hs @ Ct^T, K = SDIM
  for (int k0 = 0; k0 < SDIM; k0 += 64) {
    short8 ra[4], rb[4];
    stage_load(ra, hs, SDIM, r0, 0, k0, tid);
    stage_load(rb, Ct, SDIM, (long)c0, 0, k0, tid);
    __syncthreads();
    stage_store(lA, ra, tid);
    stage_store(lB, rb, tid);
    __syncthreads();
    mfma_Ktile(lA, lB, lane, wm, wn, acc);
  }
  // segments 1..KX: row-shifted X @ Mt[tap]^T, K = DIN
  for (int tap = 0; tap < KX; ++tap) {
    const short* Mtap = Mt + (size_t)tap * DOUT * DIN;
    for (int k0 = 0; k0 < DIN; k0 += 64) {
      short8 ra[4], rb[4];
      stage_load(ra, X, DIN, r0 - tap, bstart, k0, tid);
      stage_load(rb, Mtap, DIN, (long)c0, 0, k0, tid);
      __syncthreads();
      stage_store(lA, ra, tid);
      stage_store(lB, rb, tid);
      __syncthreads();
      mfma_Ktile(lA, lB, lane, wm, wn, acc);
    }
  }
  #pragma unroll
  for (int mi = 0; mi < 4; ++mi)
    #pragma unroll
    for (int ni = 0; ni < 4; ++ni)
      #pragma unroll
      for (int r = 0; r < 4; ++r) {
        long row = r0 + wm * 64 + mi * 16 + (lane >> 4) * 4 + r;
        int  col = c0 + wn * 64 + ni * 16 + (lane & 15);
        out[(size_t)row * DOUT + col] = acc[mi][ni][r];
      }
}

// ================= launch =================
extern "C" void kernel_launch(void* const* d_in, const int* in_sizes, int n_in,
                              void* d_out, int out_size, void* d_ws, size_t ws_size,
                              hipStream_t stream) {
  (void)in_sizes; (void)n_in; (void)out_size; (void)ws_size;
  const float* x  = (const float*)d_in[0];
  const float* h0 = (const float*)d_in[1];
  const float* A  = (const float*)d_in[2];
  const float* B  = (const float*)d_in[3];
  const float* C  = (const float*)d_in[4];
  const float* M  = (const float*)d_in[5];
  float* out = (float*)d_out;
  char* ws = (char*)d_ws;

  short* Xbf = (short*)(ws + OFF_XBF);
  float* uB  = (float*)(ws + OFF_UB);
  short* hsb = (short*)(ws + OFF_HS);
  short* Bt  = (short*)(ws + OFF_BT);
  short* Ct  = (short*)(ws + OFF_CT);
  short* Mt  = (short*)(ws + OFF_MT);
  float* E   = (float*)(ws + OFF_E);
  float* Sb  = (float*)(ws + OFF_SB);

  // prep
  k_conv_x<<<2048, 256, 0, stream>>>(x, Xbf, RTOT * DIN / 8);
  k_transpose_bf16<<<dim3(SDIM / 32, DIN / 32), 256, 0, stream>>>(B, Bt, DIN, SDIM);
  k_transpose_bf16<<<dim3(DOUT / 32, SDIM / 32), 256, 0, stream>>>(C, Ct, SDIM, DOUT);
  k_prep_M<<<(DOUT * DIN + 255) / 256, 256, 0, stream>>>(M, Mt);

  // input projection
  k_gemm_uB<<<dim3(RTOT / 128, SDIM / 128), 256, 0, stream>>>(Xbf, Bt, uB);

  // chunked diagonal scan
  k_scan_E<<<B_SZ * NC, 256, 0, stream>>>(uB, A, E);
  k_scan_S<<<B_SZ, 256, 0, stream>>>(E, A, h0, Sb);
  k_scan_h<<<B_SZ * NC, 256, 0, stream>>>(uB, A, Sb, hsb);

  // output projection + AR conv
  k_gemm_out<<<dim3(RTOT / 128, DOUT / 128), 256, 0, stream>>>(hsb, Xbf, Ct, Mt, out);
}

// Round 3
// 178.407 us; speedup vs baseline: 1.2664x; 1.2664x over previous
//
#include <hip/hip_runtime.h>

#define B_SZ   8
#define SEQ    2048
#define PSEQ   (SEQ+16)     // 16 zero pad rows before each batch
#define SDIM   1024
#define DIN    512
#define DOUT   512
#define KX     10
#define RTOT   (B_SZ*SEQ)   // 16384
#define LC     64
#define NC     (SEQ/LC)     // 32

typedef __attribute__((ext_vector_type(8))) short short8;
typedef __attribute__((ext_vector_type(4))) float f32x4;
typedef __attribute__((ext_vector_type(4))) unsigned short bfx4;

// ---- workspace layout (bytes) ----
#define OFF_XP   0UL             // B_SZ*PSEQ*DIN*2      = 16,908,288
#define OFF_UB   16908288UL      // RTOT*SDIM*2 (bf16)   = 33,554,432
#define OFF_HS   50462720UL      // RTOT*SDIM*2 (bf16)   = 33,554,432
#define OFF_BT   84017152UL      // SDIM*DIN*2           = 1,048,576
#define OFF_CT   85065728UL      // DOUT*SDIM*2          = 1,048,576
#define OFF_MT   86114304UL      // KX*DOUT*DIN*2        = 5,242,880
// total ws: 91,357,184 bytes.  E/Sb live in d_out (overwritten by k_gemm_out).

__device__ __forceinline__ short f2bf(float f) {
  unsigned u = __builtin_bit_cast(unsigned, f);
  u += 0x7fffu + ((u >> 16) & 1u);   // RNE
  return (short)(u >> 16);
}
__device__ __forceinline__ float bf2f(unsigned short b) {
  return __builtin_bit_cast(float, (unsigned)b << 16);
}

#define GLOAD16(gp, lp) __builtin_amdgcn_global_load_lds( \
    (const __attribute__((address_space(1))) void*)(gp), \
    (__attribute__((address_space(3))) void*)(lp), 16, 0, 0)

// ================= conversion / prep =================
// x [RTOT][DIN] f32 -> Xpad [b][16+t][DIN] bf16
__global__ void k_conv_x(const float* __restrict__ in, short* __restrict__ out) {
  const int NG = RTOT * (DIN / 8);
  for (int g = blockIdx.x * 256 + threadIdx.x; g < NG; g += 2048 * 256) {
    int r = g >> 6, c8 = g & 63;
    int b = r >> 11, t = r & 2047;
    const float4* p = reinterpret_cast<const float4*>(in) + (size_t)g * 2;
    float4 f0 = p[0], f1 = p[1];
    short8 o;
    o[0]=f2bf(f0.x); o[1]=f2bf(f0.y); o[2]=f2bf(f0.z); o[3]=f2bf(f0.w);
    o[4]=f2bf(f1.x); o[5]=f2bf(f1.y); o[6]=f2bf(f1.z); o[7]=f2bf(f1.w);
    *reinterpret_cast<short8*>(out + ((size_t)(b * PSEQ + 16 + t) * DIN + c8 * 8)) = o;
  }
}

// zero the 16 pad rows per batch
__global__ void k_zero_pad(short* __restrict__ Xp) {
  int idx = blockIdx.x * 256 + threadIdx.x;   // 8192 short8 groups
  if (idx >= B_SZ * 16 * (DIN / 8)) return;
  int b = idx >> 10, rem = idx & 1023;        // 16*64 = 1024 per batch
  int row16 = rem >> 6, c8 = rem & 63;
  const short8 z = {0,0,0,0,0,0,0,0};
  *reinterpret_cast<short8*>(Xp + ((size_t)(b * PSEQ + row16) * DIN + c8 * 8)) = z;
}

// out[j][i] = bf16(in[i][j]); in: rows x cols (multiples of 32)
__global__ void k_transpose_bf16(const float* __restrict__ in, short* __restrict__ out,
                                 int rows, int cols) {
  __shared__ float t[32][33];
  int bx = blockIdx.x * 32, by = blockIdx.y * 32;
  int tx = threadIdx.x & 31, ty = threadIdx.x >> 5;
  #pragma unroll
  for (int j = 0; j < 32; j += 8)
    t[ty + j][tx] = in[(size_t)(by + ty + j) * cols + (bx + tx)];
  __syncthreads();
  #pragma unroll
  for (int j = 0; j < 32; j += 8)
    out[(size_t)(bx + ty + j) * rows + (by + tx)] = f2bf(t[tx][ty + j]);
}

// Mt[t][o][i] = bf16(M[o][i][t])
__global__ void k_prep_M(const float* __restrict__ M, short* __restrict__ Mt) {
  int idx = blockIdx.x * 256 + threadIdx.x;
  if (idx >= DOUT * DIN) return;
  int o = idx / DIN, i = idx - o * DIN;
  const float* src = M + ((size_t)o * DIN + i) * KX;
  #pragma unroll
  for (int t = 0; t < KX; ++t)
    Mt[((size_t)t * DOUT + o) * DIN + i] = f2bf(src[t]);
}

// ================= chunked scan (uB is bf16) =================
__global__ void k_scan_E(const short* __restrict__ uB, const float* __restrict__ A,
                         float* __restrict__ E) {
  int blk = blockIdx.x, tid = threadIdx.x;
  int b = blk >> 5, c = blk & 31;
  int s0 = tid * 4;
  const short* base = uB + ((size_t)b * SEQ + (size_t)c * LC) * SDIM + s0;
  float a[4], h[4];
  #pragma unroll
  for (int j = 0; j < 4; ++j) { a[j] = A[s0 + j]; h[j] = 0.f; }
  for (int t = 0; t < LC; ++t) {
    bfx4 v = *reinterpret_cast<const bfx4*>(base + (size_t)t * SDIM);
    #pragma unroll
    for (int j = 0; j < 4; ++j) h[j] = fmaf(a[j], h[j], bf2f(v[j]));
  }
  float* ep = E + (size_t)blk * SDIM + s0;
  #pragma unroll
  for (int j = 0; j < 4; ++j) ep[j] = h[j];
}

__global__ void k_scan_S(const float* __restrict__ E, const float* __restrict__ A,
                         const float* __restrict__ h0, float* __restrict__ Sb) {
  int blk = blockIdx.x, tid = threadIdx.x;
  int b = blk >> 2;
  int s = ((blk & 3) << 8) + tid;
  float a = A[s], ap = a;
  #pragma unroll
  for (int q = 0; q < 6; ++q) ap *= ap;   // a^64
  float S = h0[s];
  for (int c = 0; c < NC; ++c) {
    size_t idx = ((size_t)b * NC + c) * SDIM + s;
    Sb[idx] = S;
    S = fmaf(ap, S, E[idx]);
  }
}

__global__ void k_scan_h(const short* __restrict__ uB, const float* __restrict__ A,
                         const float* __restrict__ Sb, short* __restrict__ hs) {
  int blk = blockIdx.x, tid = threadIdx.x;
  int b = blk >> 5, c = blk & 31;
  int s0 = tid * 4;
  const short* base = uB + ((size_t)b * SEQ + (size_t)c * LC) * SDIM + s0;
  short* hbase = hs + ((size_t)b * SEQ + (size_t)c * LC) * SDIM + s0;
  float a[4], h[4];
  #pragma unroll
  for (int j = 0; j < 4; ++j) {
    a[j] = A[s0 + j];
    h[j] = Sb[(size_t)blk * SDIM + s0 + j];
  }
  for (int t = 0; t < LC; ++t) {
    bfx4 v = *reinterpret_cast<const bfx4*>(base + (size_t)t * SDIM);
    bfx4 o;
    #pragma unroll
    for (int j = 0; j < 4; ++j) {
      h[j] = fmaf(a[j], h[j], bf2f(v[j]));
      o[j] = (unsigned short)f2bf(h[j]);
    }
    *reinterpret_cast<bfx4*>(hbase + (size_t)t * SDIM) = o;
  }
}

// ================= MFMA GEMM (m97 structure: 128x128, BK=64, gload_lds, swizzle) ===
// LDS tile [128][64] bf16 linear (128B rows). Swizzle: 16B-slot s of row r holds
// global slot s ^ (r&7)  (involution; applied on global src AND ds_read addr).

__device__ __forceinline__ void stage32(const short* __restrict__ g0, int ld,
                                        short* l0, int w, int lane) {
  int r8 = lane >> 3;                 // row within 8-row group == row&7
  int slot = (lane & 7) ^ r8;         // pre-swizzled global 16B slot
  const char* gb = (const char*)g0 + slot * 16;
  #pragma unroll
  for (int i = 0; i < 4; ++i) {
    int row = w * 32 + i * 8;
    GLOAD16(gb + ((size_t)(row + r8) * ld) * 2, l0 + row * 64);
  }
}

__device__ __forceinline__ void mfma_Ktile_swz(const short* lA, const short* lB,
                                               int lane, int wm, int wn, f32x4 acc[4][4]) {
  int lr = lane & 15;
  int h  = lane >> 4;
  #pragma unroll
  for (int kk = 0; kk < 64; kk += 32) {
    int kslot = (kk >> 3) + h;
    short8 af[4], bfr[4];
    #pragma unroll
    for (int mi = 0; mi < 4; ++mi) {
      int row = wm * 64 + mi * 16 + lr;
      af[mi] = *reinterpret_cast<const short8*>(lA + row * 64 + ((kslot ^ (row & 7)) << 3));
    }
    #pragma unroll
    for (int ni = 0; ni < 4; ++ni) {
      int row = wn * 64 + ni * 16 + lr;
      bfr[ni] = *reinterpret_cast<const short8*>(lB + row * 64 + ((kslot ^ (row & 7)) << 3));
    }
    #pragma unroll
    for (int mi = 0; mi < 4; ++mi)
      #pragma unroll
      for (int ni = 0; ni < 4; ++ni)
        acc[mi][ni] = __builtin_amdgcn_mfma_f32_16x16x32_bf16(af[mi], bfr[ni], acc[mi][ni], 0, 0, 0);
  }
}

// GEMM1: uB[R,SDIM] (bf16) = Xpad-rows @ Bt[SDIM,DIN]^T
__global__ __launch_bounds__(256) void k_gemm_uB(const short* __restrict__ Xp,
                                                 const short* __restrict__ Bt,
                                                 short* __restrict__ uB) {
  __shared__ __attribute__((aligned(16))) short lA[128 * 64];
  __shared__ __attribute__((aligned(16))) short lB[128 * 64];
  int tid = threadIdx.x, lane = tid & 63, w = tid >> 6, wm = w >> 1, wn = w & 1;
  long r0 = (long)blockIdx.x * 128;
  int  c0 = blockIdx.y * 128;
  int  b  = (int)(r0 >> 11);
  const short* Abase = Xp + (size_t)(r0 + 16 * (b + 1)) * DIN;
  const f32x4 z4 = {0.f, 0.f, 0.f, 0.f};
  f32x4 acc[4][4];
  #pragma unroll
  for (int mi = 0; mi < 4; ++mi)
    #pragma unroll
    for (int ni = 0; ni < 4; ++ni) acc[mi][ni] = z4;

  for (int k0 = 0; k0 < DIN; k0 += 64) {
    stage32(Abase + k0, DIN, lA, w, lane);
    stage32(Bt + (size_t)c0 * DIN + k0, DIN, lB, w, lane);
    __syncthreads();
    mfma_Ktile_swz(lA, lB, lane, wm, wn, acc);
    __syncthreads();
  }
  #pragma unroll
  for (int mi = 0; mi < 4; ++mi)
    #pragma unroll
    for (int ni = 0; ni < 4; ++ni)
      #pragma unroll
      for (int r = 0; r < 4; ++r) {
        long row = r0 + wm * 64 + mi * 16 + (lane >> 4) * 4 + r;
        int  col = c0 + wn * 64 + ni * 16 + (lane & 15);
        uB[(size_t)row * SDIM + col] = f2bf(acc[mi][ni][r]);
      }
}

// GEMM2: out = hs @ Ct^T + sum_tap Xshift @ Mt[tap]^T
__global__ __launch_bounds__(256) void k_gemm_out(const short* __restrict__ hs,
                                                  const short* __restrict__ Xp,
                                                  const short* __restrict__ Ct,
                                                  const short* __restrict__ Mt,
                                                  float* __restrict__ out) {
  __shared__ __attribute__((aligned(16))) short lA[128 * 64];
  __shared__ __attribute__((aligned(16))) short lB[128 * 64];
  int tid = threadIdx.x, lane = tid & 63, w = tid >> 6, wm = w >> 1, wn = w & 1;
  long r0 = (long)blockIdx.x * 128;
  int  c0 = blockIdx.y * 128;
  int  b  = (int)(r0 >> 11);
  const f32x4 z4 = {0.f, 0.f, 0.f, 0.f};
  f32x4 acc[4][4];
  #pragma unroll
  for (int mi = 0; mi < 4; ++mi)
    #pragma unroll
    for (int ni = 0; ni < 4; ++ni) acc[mi][ni] = z4;

  // segment 0: hs @ Ct^T, K = SDIM
  for (int k0 = 0; k0 < SDIM; k0 += 64) {
    stage32(hs + (size_t)r0 * SDIM + k0, SDIM, lA, w, lane);
    stage32(Ct + (size_t)c0 * SDIM + k0, SDIM, lB, w, lane);
    __syncthreads();
    mfma_Ktile_swz(lA, lB, lane, wm, wn, acc);
    __syncthreads();
  }
  // segments 1..KX: shifted Xpad @ Mt[tap]^T, K = DIN (pad rows are zeros)
  for (int tap = 0; tap < KX; ++tap) {
    const short* Abase = Xp + (size_t)(r0 + 16 * (b + 1) - tap) * DIN;
    const short* Bbase = Mt + (size_t)tap * DOUT * DIN + (size_t)c0 * DIN;
    for (int k0 = 0; k0 < DIN; k0 += 64) {
      stage32(Abase + k0, DIN, lA, w, lane);
      stage32(Bbase + k0, DIN, lB, w, lane);
      __syncthreads();
      mfma_Ktile_swz(lA, lB, lane, wm, wn, acc);
      __syncthreads();
    }
  }
  #pragma unroll
  for (int mi = 0; mi < 4; ++mi)
    #pragma unroll
    for (int ni = 0; ni < 4; ++ni)
      #pragma unroll
      for (int r = 0; r < 4; ++r) {
        long row = r0 + wm * 64 + mi * 16 + (lane >> 4) * 4 + r;
        int  col = c0 + wn * 64 + ni * 16 + (lane & 15);
        out[(size_t)row * DOUT + col] = acc[mi][ni][r];
      }
}

// ================= launch =================
extern "C" void kernel_launch(void* const* d_in, const int* in_sizes, int n_in,
                              void* d_out, int out_size, void* d_ws, size_t ws_size,
                              hipStream_t stream) {
  (void)in_sizes; (void)n_in; (void)out_size; (void)ws_size;
  const float* x  = (const float*)d_in[0];
  const float* h0 = (const float*)d_in[1];
  const float* A  = (const float*)d_in[2];
  const float* B  = (const float*)d_in[3];
  const float* C  = (const float*)d_in[4];
  const float* M  = (const float*)d_in[5];
  float* out = (float*)d_out;
  char* ws = (char*)d_ws;

  short* Xp  = (short*)(ws + OFF_XP);
  short* uB  = (short*)(ws + OFF_UB);
  short* hsb = (short*)(ws + OFF_HS);
  short* Bt  = (short*)(ws + OFF_BT);
  short* Ct  = (short*)(ws + OFF_CT);
  short* Mt  = (short*)(ws + OFF_MT);
  // scan scratch inside d_out (fully overwritten by k_gemm_out afterwards)
  float* E   = out;                    // B_SZ*NC*SDIM f32 = 1 MiB
  float* Sb  = out + B_SZ * NC * SDIM; // 1 MiB

  k_conv_x<<<2048, 256, 0, stream>>>(x, Xp);
  k_zero_pad<<<32, 256, 0, stream>>>(Xp);
  k_transpose_bf16<<<dim3(SDIM / 32, DIN / 32), 256, 0, stream>>>(B, Bt, DIN, SDIM);
  k_transpose_bf16<<<dim3(DOUT / 32, SDIM / 32), 256, 0, stream>>>(C, Ct, SDIM, DOUT);
  k_prep_M<<<(DOUT * DIN + 255) / 256, 256, 0, stream>>>(M, Mt);

  k_gemm_uB<<<dim3(RTOT / 128, SDIM / 128), 256, 0, stream>>>(Xp, Bt, uB);

  k_scan_E<<<B_SZ * NC, 256, 0, stream>>>(uB, A, E);
  k_scan_S<<<B_SZ * 4, 256, 0, stream>>>(E, A, h0, Sb);
  k_scan_h<<<B_SZ * NC, 256, 0, stream>>>(uB, A, Sb, hsb);

  k_gemm_out<<<dim3(RTOT / 128, DOUT / 128), 256, 0, stream>>>(hsb, Xp, Ct, Mt, out);
}